// Round 12
// baseline (296.062 us; speedup 1.0000x reference)
//
#include <hip/hip_runtime.h>
#include <hip/hip_bf16.h>
#include <cstdint>

#define B_ 8
#define S_ 4096
#define DM 1024
#define H_ 16
#define DN 64      // head dim
#define CH 64      // chunk length
#define NC 64      // chunks per sequence
#define M_ (B_ * S_)

typedef unsigned short u16;
typedef u16 u16x8 __attribute__((ext_vector_type(8)));
typedef u16 u16x4 __attribute__((ext_vector_type(4)));
typedef float f32x4 __attribute__((ext_vector_type(4)));
typedef __bf16 bf16x8 __attribute__((ext_vector_type(8)));

__device__ __forceinline__ float bf2f(u16 u) { return __uint_as_float(((unsigned)u) << 16); }
__device__ __forceinline__ u16 f2bf(float f) { __bf16 h = (__bf16)f; return __builtin_bit_cast(u16, h); }

#define GLOAD16(gp, lp) \
  __builtin_amdgcn_global_load_lds((__attribute__((address_space(1))) const void*)(gp), \
                                   (__attribute__((address_space(3))) void*)(lp), 16, 0, 0)
#define BAR()   asm volatile("s_barrier" ::: "memory")
#define VMCNT6() asm volatile("s_waitcnt vmcnt(6)" ::: "memory")
#define VMCNT0() asm volatile("s_waitcnt vmcnt(0)" ::: "memory")
#define LGKM0()  asm volatile("s_waitcnt lgkmcnt(0)" ::: "memory")

// ===================== 256x256 8-phase bf16 MFMA GEMM (T1+T2+T3+T4+T5) =====================
__device__ __forceinline__ void stage_unit(const u16* __restrict__ src, int row0, int kt,
                                           int ks, u16* ldsu, int t, int K) {
#pragma unroll
  for (int i = 0; i < 2; ++i) {
    int f = i * 512 + t;
    int row = f >> 2, j = f & 3;
    int g = j ^ ((row >> 1) & 3);
    GLOAD16(src + (size_t)(row0 + row) * K + kt * 64 + ks * 32 + g * 8, ldsu + f * 8);
  }
}

__device__ __forceinline__ void lda4(bf16x8* fr, const u16* unit, int rbase, int lr, int lk) {
#pragma unroll
  for (int q = 0; q < 4; ++q) {
    int row = rbase + q * 16 + lr;
    int cell = row * 4 + (lk ^ ((row >> 1) & 3));
    fr[q] = *reinterpret_cast<const bf16x8*>(&unit[cell * 8]);
  }
}

__device__ __forceinline__ void mfma16(f32x4 (&acc)[8][4], int mh, const bf16x8* aF, const bf16x8* bF) {
  __builtin_amdgcn_s_setprio(1);
#pragma unroll
  for (int q = 0; q < 4; ++q)
#pragma unroll
    for (int nf = 0; nf < 4; ++nf)
      acc[mh * 4 + q][nf] = __builtin_amdgcn_mfma_f32_16x16x32_bf16(aF[q], bF[nf], acc[mh * 4 + q][nf], 0, 0, 0);
  __builtin_amdgcn_s_setprio(0);
}

template<int MODE>  // 0: fp32 out (direct, already 64B-coalesced), 1: bf16 out (LDS epilogue)
__global__ __launch_bounds__(512, 2) void bgemm8(
    const u16* __restrict__ A, const u16* __restrict__ Bw,
    void* __restrict__ Cout, int K)
{
  // K-loop: 8 units of 8192 u16 (128 KB). Epilogue (MODE=1): [256][264] u16 (132 KB).
  __shared__ u16 smem[67584];
  const int orig = blockIdx.x;                        // 512 blocks, 512 % 8 == 0
  const int swz  = (orig & 7) * 64 + (orig >> 3);     // XCD-bijective
  const int m0 = (swz >> 2) * 256;
  const int n0 = (swz & 3) * 256;
  const int t  = threadIdx.x;
  const int wid = t >> 6, l = t & 63;
  const int wm = wid >> 2, wn = wid & 3;
  const int lr = l & 15, lk = l >> 4;
  const int arb = wm * 128;     // A row base for this wave
  const int brb = wn * 64;      // B row base
  u16* lds0 = smem;             // unit u at smem + u*8192
#define UNIT(u) (lds0 + (u) * 8192)

  f32x4 acc[8][4];
#pragma unroll
  for (int i = 0; i < 8; ++i)
#pragma unroll
    for (int j = 0; j < 4; ++j) acc[i][j] = (f32x4){0.f, 0.f, 0.f, 0.f};

  // prologue: T0 fully + B0,B1,A0 of T1  (7 half-units, oldest first)
  stage_unit(A,  m0, 0, 0, UNIT(0), t, K);
  stage_unit(A,  m0, 0, 1, UNIT(1), t, K);
  stage_unit(Bw, n0, 0, 0, UNIT(2), t, K);
  stage_unit(Bw, n0, 0, 1, UNIT(3), t, K);
  stage_unit(Bw, n0, 1, 0, UNIT(6), t, K);
  stage_unit(Bw, n0, 1, 1, UNIT(7), t, K);
  stage_unit(A,  m0, 1, 0, UNIT(4), t, K);
  VMCNT6();   // T0's 4 units landed
  BAR();

  bf16x8 aF[4], bF0[4], bF1[4];
  for (int i = 0; i < 8; ++i) {
    const bool st = (i < 7);
    // ---- tile 2i from buf0 ----
    lda4(aF, UNIT(0), arb, lr, lk);
    lda4(bF0, UNIT(2), brb, lr, lk);
    stage_unit(A, m0, 2 * i + 1, 1, UNIT(5), t, K);          // A1(T1)
    BAR(); mfma16(acc, 0, aF, bF0); BAR();
    lda4(aF, UNIT(1), arb, lr, lk);
    lda4(bF1, UNIT(3), brb, lr, lk);
    if (st) stage_unit(Bw, n0, 2 * i + 2, 0, UNIT(2), t, K); // B0(T2)
    BAR(); mfma16(acc, 0, aF, bF1); BAR();
    lda4(aF, UNIT(0), arb + 64, lr, lk);
    if (st) stage_unit(Bw, n0, 2 * i + 2, 1, UNIT(3), t, K); // B1(T2)
    BAR(); mfma16(acc, 1, aF, bF0); BAR();
    lda4(aF, UNIT(1), arb + 64, lr, lk);
    if (st) { stage_unit(A, m0, 2 * i + 2, 0, UNIT(0), t, K); VMCNT6(); }  // A0(T2)
    else    { VMCNT0(); }
    BAR(); mfma16(acc, 1, aF, bF1); BAR();
    // ---- tile 2i+1 from buf1 ----
    lda4(aF, UNIT(4), arb, lr, lk);
    lda4(bF0, UNIT(6), brb, lr, lk);
    if (st) stage_unit(A, m0, 2 * i + 2, 1, UNIT(1), t, K);  // A1(T2)
    BAR(); mfma16(acc, 0, aF, bF0); BAR();
    lda4(aF, UNIT(5), arb, lr, lk);
    lda4(bF1, UNIT(7), brb, lr, lk);
    if (st) stage_unit(Bw, n0, 2 * i + 3, 0, UNIT(6), t, K); // B0(T3)
    BAR(); mfma16(acc, 0, aF, bF1); BAR();
    lda4(aF, UNIT(4), arb + 64, lr, lk);
    if (st) stage_unit(Bw, n0, 2 * i + 3, 1, UNIT(7), t, K); // B1(T3)
    BAR(); mfma16(acc, 1, aF, bF0); BAR();
    lda4(aF, UNIT(5), arb + 64, lr, lk);
    if (st) { stage_unit(A, m0, 2 * i + 3, 0, UNIT(4), t, K); VMCNT6(); }  // A0(T3)
    BAR(); mfma16(acc, 1, aF, bF1); BAR();
  }

  if (MODE == 0) {
    // fp32 direct: 16 lanes x 4B = full 64B sectors, no amplification
#pragma unroll
    for (int mf = 0; mf < 8; ++mf)
#pragma unroll
      for (int nf = 0; nf < 4; ++nf) {
        int n  = n0 + wn * 64 + nf * 16 + lr;
        int mb = m0 + wm * 128 + mf * 16 + lk * 4;
#pragma unroll
        for (int r = 0; r < 4; ++r)
          ((float*)Cout)[(size_t)(mb + r) * 1024 + n] = acc[mf][nf][r];
      }
  } else {
    // bf16 via LDS transpose: scatter frags to [256][264] u16 (row stride 528B =
    // 4-bank rotation), then stream 256B contiguous runs per thread -> full sectors.
#pragma unroll
    for (int mf = 0; mf < 8; ++mf)
#pragma unroll
      for (int nf = 0; nf < 4; ++nf) {
        int rl = wm * 128 + mf * 16 + lk * 4;
        int cl = wn * 64 + nf * 16 + lr;
#pragma unroll
        for (int r = 0; r < 4; ++r)
          smem[(rl + r) * 264 + cl] = f2bf(acc[mf][nf][r]);
      }
    LGKM0(); BAR();
    {
      int row = t >> 1, half = t & 1;
      u16* gp = (u16*)Cout + (size_t)(m0 + row) * 1024 + n0 + half * 128;
      const u16* lp = &smem[row * 264 + half * 128];
#pragma unroll
      for (int j = 0; j < 16; ++j)
        *reinterpret_cast<u16x8*>(gp + j * 8) = *reinterpret_cast<const u16x8*>(lp + j * 8);
    }
  }
#undef UNIT
}

// ===================== prep: weights->bf16 + w-row residuals, one kernel =====================
// blocks [0,520): in_proj bf16; [520,1032): out_proj bf16; [1032,1040): wlo residuals
__global__ __launch_bounds__(256) void prep_kernel(
    const float* __restrict__ ipw, const float* __restrict__ opw,
    u16* __restrict__ wbf_in, u16* __restrict__ wbf_out, u16* __restrict__ wlo)
{
  int b = blockIdx.x;
  if (b < 1032) {
    const float* src = (b < 520) ? ipw : opw;
    u16* dst = (b < 520) ? wbf_in : wbf_out;
    size_t i = ((size_t)(b < 520 ? b : b - 520) * 256 + threadIdx.x) * 8;
    f32x4 a = *reinterpret_cast<const f32x4*>(&src[i]);
    f32x4 c = *reinterpret_cast<const f32x4*>(&src[i + 4]);
    u16x8 o;
#pragma unroll
    for (int j = 0; j < 4; ++j) { o[j] = f2bf(a[j]); o[4 + j] = f2bf(c[j]); }
    *reinterpret_cast<u16x8*>(&dst[i]) = o;
  } else {
    size_t e = ((size_t)(b - 1032) * 256 + threadIdx.x) * 8;
    f32x4 a = *reinterpret_cast<const f32x4*>(&ipw[1048576 + e]);
    f32x4 c = *reinterpret_cast<const f32x4*>(&ipw[1048576 + e + 4]);
    u16x8 o;
#pragma unroll
    for (int j = 0; j < 4; ++j) {
      u16 h = f2bf(a[j]); o[j]     = f2bf(a[j] - bf2f(h));
      u16 g = f2bf(c[j]); o[4 + j] = f2bf(c[j] - bf2f(g));
    }
    *reinterpret_cast<u16x8*>(&wlo[e]) = o;
  }
}

// ===================== wsplit v4: K-split 4-wave x->bf16 + compensated w proj =====================
__global__ __launch_bounds__(256) void wsplit(
    const float* __restrict__ x, const u16* __restrict__ wbf, const u16* __restrict__ wlo,
    u16* __restrict__ xbf, float* __restrict__ wbufT)
{
  __shared__ u16 hi[4][16 * 5 * 8];   // 1.25 KB per wave
  __shared__ u16 lo[4][16 * 5 * 8];
  __shared__ float comb[3][64][4];
  const int t = threadIdx.x;
  const int w = t >> 6, l = t & 63;
  const int r0 = blockIdx.x * 16;
  const int k0 = w * 256;                   // this wave's k-quarter
  const int lr = l & 15, lk = l >> 4;
  const int srow = l >> 2, skc = l & 3;     // staging: lane -> row, k-chunk (8 floats)
  u16* HI = hi[w];
  u16* LO = lo[w];

  const float* gx  = &x[(size_t)(r0 + srow) * 1024 + k0 + skc * 8];
  const u16*   gbh = &wbf[(size_t)(1024 + lr) * 1024 + k0 + lk * 8];
  const u16*   gbl = &wlo[(size_t)lr * 1024 + k0 + lk * 8];

  f32x4 a0 = *reinterpret_cast<const f32x4*>(gx);
  f32x4 a1 = *reinterpret_cast<const f32x4*>(gx + 4);
  bf16x8 bh = *reinterpret_cast<const bf16x8*>(gbh);
  bf16x8 bl = *reinterpret_cast<const bf16x8*>(gbl);

  f32x4 acc = (f32x4){0.f, 0.f, 0.f, 0.f};
  const int wcell = srow * 5 + skc;
  const int rcell = lr * 5 + lk;

  for (int kt = 0; kt < 8; ++kt) {
    f32x4 n0, n1; bf16x8 nbh, nbl;
    if (kt < 7) {                  // prefetch next k-tile (x + w slices)
      n0  = *reinterpret_cast<const f32x4*>(gx + (kt + 1) * 32);
      n1  = *reinterpret_cast<const f32x4*>(gx + (kt + 1) * 32 + 4);
      nbh = *reinterpret_cast<const bf16x8*>(gbh + (kt + 1) * 32);
      nbl = *reinterpret_cast<const bf16x8*>(gbl + (kt + 1) * 32);
    }
    u16x8 h8, l8;
#pragma unroll
    for (int j = 0; j < 4; ++j) {
      u16 ha = f2bf(a0[j]); h8[j]     = ha; l8[j]     = f2bf(a0[j] - bf2f(ha));
      u16 hb = f2bf(a1[j]); h8[4 + j] = hb; l8[4 + j] = f2bf(a1[j] - bf2f(hb));
    }
    *reinterpret_cast<u16x8*>(&xbf[(size_t)(r0 + srow) * 1024 + k0 + kt * 32 + skc * 8]) = h8;
    *reinterpret_cast<u16x8*>(&HI[wcell * 8]) = h8;
    *reinterpret_cast<u16x8*>(&LO[wcell * 8]) = l8;
    asm volatile("s_waitcnt lgkmcnt(0)" ::: "memory");
    __builtin_amdgcn_sched_barrier(0);         // rule #18: pin MFMA below the wait
    bf16x8 ah = *reinterpret_cast<const bf16x8*>(&HI[rcell * 8]);
    bf16x8 al = *reinterpret_cast<const bf16x8*>(&LO[rcell * 8]);
    acc = __builtin_amdgcn_mfma_f32_16x16x32_bf16(ah, bh, acc, 0, 0, 0);
    acc = __builtin_amdgcn_mfma_f32_16x16x32_bf16(al, bh, acc, 0, 0, 0);
    acc = __builtin_amdgcn_mfma_f32_16x16x32_bf16(ah, bl, acc, 0, 0, 0);
    a0 = n0; a1 = n1; bh = nbh; bl = nbl;
  }
  // combine k-quarter partials, then store: h=lr, m = r0 + lk*4 + r
  if (w) {
#pragma unroll
    for (int r = 0; r < 4; ++r) comb[w - 1][l][r] = acc[r];
  }
  __syncthreads();
  if (!w) {
#pragma unroll
    for (int r = 0; r < 4; ++r) acc[r] += comb[0][l][r] + comb[1][l][r] + comb[2][l][r];
    *reinterpret_cast<f32x4*>(&wbufT[(size_t)lr * M_ + r0 + lk * 4]) = acc;
  }
}

// ===================== fused per-(b,h,c): conv + cumsum + L(MFMA) + Y_diag + norm + states =====================
__global__ __launch_bounds__(256) void chunk_kernel(
    const u16* __restrict__ xi,        // [M][1024] bf16 (in_proj out, pre-conv)
    const float* __restrict__ cw, const float* __restrict__ cb,
    const float* __restrict__ wbufT, const float* __restrict__ w_base,
    u16* __restrict__ ybuf, float* __restrict__ Acum, float* __restrict__ acbuf,
    float* __restrict__ normd, float* __restrict__ states, float* __restrict__ ndbuf)
{
  int bi = blockIdx.x;               // b*1024 + h*64 + c
  int c  = bi & 63;
  int h  = (bi >> 6) & 15;
  int b  = bi >> 10;
  int bh = b * 16 + h;
  int t  = threadIdx.x;
  __shared__ u16 xis[67][64];        // raw xi tile (halo 3), bf16
  __shared__ u16 xsT[64][66];        // conv output, transposed [n][s], bf16
  __shared__ float pc[CH], m1s[CH], dsv[CH];
  __shared__ float wls[4][64];       // conv weights transposed [tap][ch]
  __shared__ float cbs[64];
  size_t m0 = (size_t)b * S_ + (size_t)c * CH;
  size_t abase = ((size_t)bh * NC + c) * CH;

  wls[t & 3][t >> 2] = cw[(size_t)h * 256 + t];
  if (t < 64) cbs[t] = cb[h * 64 + t];

  {
    int g8  = t & 7;
    int hr0 = t >> 3;
    for (int hr = hr0; hr < 67; hr += 32) {
      u16x8 v = {0, 0, 0, 0, 0, 0, 0, 0};
      if (!(c == 0 && hr < 3))
        v = *reinterpret_cast<const u16x8*>(&xi[(m0 - 3 + hr) * DM + h * 64 + g8 * 8]);
      *reinterpret_cast<u16x8*>(&xis[hr][g8 * 8]) = v;
    }
  }

  if (t < 64) {
    float p = wbufT[(size_t)h * M_ + m0 + t] * w_base[h];
#pragma unroll
    for (int off = 1; off < 64; off <<= 1) {
      float v = __shfl_up(p, off);
      if (t >= off) p += v;
    }
    Acum[abase + t] = p;
    if (t == 63) acbuf[(size_t)bh * NC + c] = p;
    pc[t] = p;
    float rmin = p;
#pragma unroll
    for (int off = 1; off < 64; off <<= 1) {
      float v = __shfl_up(rmin, off);
      if (t >= off) rmin = fminf(rmin, v);
    }
    m1s[t] = p - rmin;
    float minall = __shfl(rmin, 63);
    dsv[t] = __expf(minall - p);
  }
  __syncthreads();

  // conv: thread owns channel n, 16 consecutive rows; sliding 4-tap window
  {
    int n  = t & 63;
    int lb = (t >> 6) * 16;
    float w0 = wls[0][n], w1 = wls[1][n], w2 = wls[2][n], w3 = wls[3][n];
    float bias = cbs[n];
    float a = bf2f(xis[lb + 0][n]);
    float bv = bf2f(xis[lb + 1][n]);
    float cv = bf2f(xis[lb + 2][n]);
    u16x8 o0, o1;
#pragma unroll
    for (int r = 0; r < 16; ++r) {
      float dv = bf2f(xis[lb + r + 3][n]);
      float s = fmaf(w3, dv, fmaf(w2, cv, fmaf(w1, bv, fmaf(w0, a, bias))));
      if (r < 8) o0[r] = f2bf(s); else o1[r - 8] = f2bf(s);
      a = bv; bv = cv; cv = dv;
    }
    *reinterpret_cast<u16x8*>(&xsT[n][lb]) = o0;
    *reinterpret_cast<u16x8*>(&xsT[n][lb + 8]) = o1;
  }
  __syncthreads();

  // MFMA phase: wave w owns output rows w*16..w*16+15.
  {
    int w = t >> 6, l = t & 63;
    int lr = l & 15, lk = l >> 4;
    int row = w * 16 + lr;
    float pr = pc[row], m1r = m1s[row];
    bf16x8 afr[2];
    float np = 0.f;
#pragma unroll
    for (int ks = 0; ks < 2; ++ks) {
      int sbase = ks * 32 + lk * 8;
      u16x8 av;
#pragma unroll
      for (int j = 0; j < 8; ++j) {
        int s = sbase + j;
        float L = (s <= row) ? __expf(pr - pc[s] - m1r) : 0.f;
        np += L;
        av[j] = f2bf(L);
      }
      afr[ks] = __builtin_bit_cast(bf16x8, av);
    }
    np += __shfl_xor(np, 16);
    np += __shfl_xor(np, 32);
    if (lk == 0) normd[abase + row] = np;

    f32x4 acc[4];
#pragma unroll
    for (int nf = 0; nf < 4; ++nf) acc[nf] = (f32x4){0.f, 0.f, 0.f, 0.f};
#pragma unroll
    for (int ks = 0; ks < 2; ++ks)
#pragma unroll
      for (int nf = 0; nf < 4; ++nf) {
        bf16x8 bfr = *reinterpret_cast<const bf16x8*>(&xsT[nf * 16 + lr][ks * 32 + lk * 8]);
        acc[nf] = __builtin_amdgcn_mfma_f32_16x16x32_bf16(afr[ks], bfr, acc[nf], 0, 0, 0);
      }
#pragma unroll
    for (int nf = 0; nf < 4; ++nf)
#pragma unroll
      for (int r = 0; r < 4; ++r)
        ybuf[(m0 + w * 16 + lk * 4 + r) * DM + h * 64 + nf * 16 + lr] = f2bf(acc[nf][r]);
  }

  if (t < 64) {
    float acc = 0.f;
#pragma unroll
    for (int l8 = 0; l8 < 64; l8 += 8) {
      u16x8 xv = *reinterpret_cast<const u16x8*>(&xsT[t][l8]);
#pragma unroll
      for (int j = 0; j < 8; ++j) acc = fmaf(dsv[l8 + j], bf2f(xv[j]), acc);
    }
    states[((size_t)bh * NC + c) * DN + t] = acc;
    float v = dsv[t];
#pragma unroll
    for (int off = 32; off >= 1; off >>= 1) v += __shfl_down(v, off);
    if (t == 0) ndbuf[(size_t)bh * NC + c] = v;
  }
}

// ===================== inter-chunk propagation =====================
__global__ __launch_bounds__(256) void interchunk_kernel(
    const float* __restrict__ acbuf, const float* __restrict__ states,
    const float* __restrict__ ndbuf, float* __restrict__ nstates, float* __restrict__ nndbuf)
{
  int bh = blockIdx.x;
  int t  = threadIdx.x;
  __shared__ float Ssum[NC], minP[NC], ndl[NC];
  if (t < 64) {
    float ac = acbuf[(size_t)bh * NC + t];
    float S = ac;
#pragma unroll
    for (int off = 1; off < 64; off <<= 1) {
      float v = __shfl_up(S, off);
      if (t >= off) S += v;
    }
    float Pc = S - ac;
    float mp = Pc;
#pragma unroll
    for (int off = 1; off < 64; off <<= 1) {
      float v = __shfl_up(mp, off);
      if (t >= off) mp = fminf(mp, v);
    }
    Ssum[t] = S;
    minP[t] = mp;
    ndl[t]  = ndbuf[(size_t)bh * NC + t];
  }
  __syncthreads();
  int n  = t & 63;
  int r0 = t >> 6;
  for (int r = 0; r < 16; ++r) {
    int z = r0 + r * 4;
    float mpz = minP[z];
    float acc = 0.f;
    for (int j = 0; j < z; ++j) {
      float e = __expf(mpz - Ssum[j]);
      acc = fmaf(e, states[((size_t)bh * NC + j) * DN + n], acc);
    }
    nstates[((size_t)bh * NC + z) * DN + n] = acc;
  }
  if (t < 64) {
    int z = t;
    float mpz = minP[z];
    float acc = 0.f;
    for (int j = 0; j < z; ++j) acc = fmaf(__expf(mpz - Ssum[j]), ndl[j], acc);
    nndbuf[(size_t)bh * NC + z] = acc;
  }
}

// ===================== final: y = (Y_diag + states_off*sdo) / (norm_diag + nd_off*sdo) =====================
__global__ __launch_bounds__(256) void final_kernel(
    const float* __restrict__ Acum, const float* __restrict__ normd,
    const float* __restrict__ nstates, const float* __restrict__ nndbuf,
    u16* __restrict__ ybuf)
{
  int bi = blockIdx.x;
  int c  = bi & 63;
  int h  = (bi >> 6) & 15;
  int b  = bi >> 10;
  int bh = b * 16 + h;
  int t  = threadIdx.x;
  __shared__ float sdo[CH], nrm[CH], sto[DN];
  __shared__ float ndo_s;
  size_t abase = ((size_t)bh * NC + c) * CH;
  if (t < 64) {
    float p = Acum[abase + t];
    float m3 = p;
#pragma unroll
    for (int off = 32; off >= 1; off >>= 1) m3 = fmaxf(m3, __shfl_down(m3, off));
    m3 = __shfl(m3, 0);
    sdo[t] = __expf(p - m3);
    nrm[t] = normd[abase + t];
    sto[t] = nstates[((size_t)bh * NC + c) * DN + t];
    if (t == 0) ndo_s = nndbuf[(size_t)bh * NC + c];
  }
  __syncthreads();
  size_t m0 = (size_t)b * S_ + (size_t)c * CH;
  int g  = t & 7;
  int l0 = t >> 3;
  float ndo = ndo_s;
  for (int li = l0; li < 64; li += 32) {
    size_t a = (m0 + li) * DM + h * DN + g * 8;
    u16x8 v = *reinterpret_cast<u16x8*>(&ybuf[a]);
    float sd = sdo[li];
    float rec = 1.f / (nrm[li] + ndo * sd);
    u16x8 o;
#pragma unroll
    for (int jj = 0; jj < 8; ++jj) {
      float yd = bf2f(v[jj]);
      o[jj] = f2bf((yd + sto[g * 8 + jj] * sd) * rec);
    }
    *reinterpret_cast<u16x8*>(&ybuf[a]) = o;
  }
}

// ===================== launch =====================
extern "C" void kernel_launch(void* const* d_in, const int* in_sizes, int n_in,
                              void* d_out, int out_size, void* d_ws, size_t ws_size,
                              hipStream_t stream) {
  const float* x          = (const float*)d_in[0];
  const float* in_proj_w  = (const float*)d_in[1];
  const float* conv_w     = (const float*)d_in[2];
  const float* conv_b     = (const float*)d_in[3];
  const float* w_base     = (const float*)d_in[4];
  const float* out_proj_w = (const float*)d_in[5];
  float* out = (float*)d_out;
  char* ws = (char*)d_ws;

  // workspace layout (~149 MB)
  u16*   wbf_in  = (u16*)  (ws + 0);          // [1040][1024] bf16 (all in_proj rows)
  u16*   wbf_out = (u16*)  (ws + 2129920);
  u16*   wlo16   = (u16*)  (ws + 4227072);    // [16][1024] bf16 residuals
  float* wbufT   = (float*)(ws + 4259840);
  float* Acum    = (float*)(ws + 6356992);
  float* acbuf   = (float*)(ws + 8454144);
  float* normd   = (float*)(ws + 8486912);
  float* states  = (float*)(ws + 10584064);
  float* ndbuf   = (float*)(ws + 12681216);
  float* nstates = (float*)(ws + 12713984);
  float* nndbuf  = (float*)(ws + 14811136);
  u16*   xbf     = (u16*)  (ws + 14843904);   // [M][1024] bf16 of x; reused as ybuf
  u16*   xibf    = (u16*)  (ws + 81952768);   // [M][1024] bf16 xi (in_proj out)
  u16*   ybuf    = xbf;

  prep_kernel<<<1040, 256, 0, stream>>>(in_proj_w, out_proj_w, wbf_in, wbf_out, wlo16);
  wsplit<<<2048, 256, 0, stream>>>(x, wbf_in, wlo16, xbf, wbufT);
  bgemm8<1><<<512, 512, 0, stream>>>(xbf, wbf_in, (void*)xibf, DM);
  chunk_kernel<<<8192, 256, 0, stream>>>(xibf, conv_w, conv_b, wbufT, w_base,
                                         ybuf, Acum, acbuf, normd, states, ndbuf);
  interchunk_kernel<<<128, 256, 0, stream>>>(acbuf, states, ndbuf, nstates, nndbuf);
  final_kernel<<<8192, 256, 0, stream>>>(Acum, normd, nstates, nndbuf, ybuf);
  bgemm8<0><<<512, 512, 0, stream>>>(ybuf, wbf_out, (void*)out, DM);
}

// Round 13
// 286.943 us; speedup vs baseline: 1.0318x; 1.0318x over previous
//
#include <hip/hip_runtime.h>
#include <hip/hip_bf16.h>
#include <cstdint>

#define B_ 8
#define S_ 4096
#define DM 1024
#define H_ 16
#define DN 64      // head dim
#define CH 64      // chunk length
#define NC 64      // chunks per sequence
#define M_ (B_ * S_)

typedef unsigned short u16;
typedef u16 u16x8 __attribute__((ext_vector_type(8)));
typedef u16 u16x4 __attribute__((ext_vector_type(4)));
typedef float f32x4 __attribute__((ext_vector_type(4)));
typedef __bf16 bf16x8 __attribute__((ext_vector_type(8)));

__device__ __forceinline__ float bf2f(u16 u) { return __uint_as_float(((unsigned)u) << 16); }
__device__ __forceinline__ u16 f2bf(float f) { __bf16 h = (__bf16)f; return __builtin_bit_cast(u16, h); }

#define GLOAD16(gp, lp) \
  __builtin_amdgcn_global_load_lds((__attribute__((address_space(1))) const void*)(gp), \
                                   (__attribute__((address_space(3))) void*)(lp), 16, 0, 0)
#define BAR()   asm volatile("s_barrier" ::: "memory")
#define VMCNT6() asm volatile("s_waitcnt vmcnt(6)" ::: "memory")
#define VMCNT0() asm volatile("s_waitcnt vmcnt(0)" ::: "memory")

// ===================== 256x256 8-phase bf16 MFMA GEMM (T1+T2+T3+T4+T5) =====================
// Round-11 verified version (76.4 us, 900 TF, 0 bank conflicts). Round-12's LDS
// epilogue REVERTED: it added 262K conflicts + serialized b16 scatter and slowed
// both template instantiations (rule #19 codegen coupling). bf16 C write
// amplification (132 vs 64 MB) is free at 1.7 TB/s total BW — writes aren't the
// bottleneck.
__device__ __forceinline__ void stage_unit(const u16* __restrict__ src, int row0, int kt,
                                           int ks, u16* ldsu, int t, int K) {
#pragma unroll
  for (int i = 0; i < 2; ++i) {
    int f = i * 512 + t;
    int row = f >> 2, j = f & 3;
    int g = j ^ ((row >> 1) & 3);
    GLOAD16(src + (size_t)(row0 + row) * K + kt * 64 + ks * 32 + g * 8, ldsu + f * 8);
  }
}

__device__ __forceinline__ void lda4(bf16x8* fr, const u16* unit, int rbase, int lr, int lk) {
#pragma unroll
  for (int q = 0; q < 4; ++q) {
    int row = rbase + q * 16 + lr;
    int cell = row * 4 + (lk ^ ((row >> 1) & 3));
    fr[q] = *reinterpret_cast<const bf16x8*>(&unit[cell * 8]);
  }
}

__device__ __forceinline__ void mfma16(f32x4 (&acc)[8][4], int mh, const bf16x8* aF, const bf16x8* bF) {
  __builtin_amdgcn_s_setprio(1);
#pragma unroll
  for (int q = 0; q < 4; ++q)
#pragma unroll
    for (int nf = 0; nf < 4; ++nf)
      acc[mh * 4 + q][nf] = __builtin_amdgcn_mfma_f32_16x16x32_bf16(aF[q], bF[nf], acc[mh * 4 + q][nf], 0, 0, 0);
  __builtin_amdgcn_s_setprio(0);
}

template<int MODE>  // 0: fp32 out, 1: bf16 out
__global__ __launch_bounds__(512, 2) void bgemm8(
    const u16* __restrict__ A, const u16* __restrict__ Bw,
    void* __restrict__ Cout, int K)
{
  __shared__ u16 lds[8][8192];   // units: 0:A0b0 1:A1b0 2:B0b0 3:B1b0 4:A0b1 5:A1b1 6:B0b1 7:B1b1
  const int orig = blockIdx.x;                        // 512 blocks, 512 % 8 == 0
  const int swz  = (orig & 7) * 64 + (orig >> 3);     // XCD-bijective
  const int m0 = (swz >> 2) * 256;
  const int n0 = (swz & 3) * 256;
  const int t  = threadIdx.x;
  const int wid = t >> 6, l = t & 63;
  const int wm = wid >> 2, wn = wid & 3;
  const int lr = l & 15, lk = l >> 4;
  const int arb = wm * 128;     // A row base for this wave
  const int brb = wn * 64;      // B row base

  f32x4 acc[8][4];
#pragma unroll
  for (int i = 0; i < 8; ++i)
#pragma unroll
    for (int j = 0; j < 4; ++j) acc[i][j] = (f32x4){0.f, 0.f, 0.f, 0.f};

  // prologue: T0 fully + B0,B1,A0 of T1  (7 half-units, oldest first)
  stage_unit(A,  m0, 0, 0, lds[0], t, K);
  stage_unit(A,  m0, 0, 1, lds[1], t, K);
  stage_unit(Bw, n0, 0, 0, lds[2], t, K);
  stage_unit(Bw, n0, 0, 1, lds[3], t, K);
  stage_unit(Bw, n0, 1, 0, lds[6], t, K);
  stage_unit(Bw, n0, 1, 1, lds[7], t, K);
  stage_unit(A,  m0, 1, 0, lds[4], t, K);
  VMCNT6();   // T0's 4 units landed
  BAR();

  bf16x8 aF[4], bF0[4], bF1[4];
  for (int i = 0; i < 8; ++i) {
    const bool st = (i < 7);
    // ---- tile 2i from buf0 ----
    lda4(aF, lds[0], arb, lr, lk);
    lda4(bF0, lds[2], brb, lr, lk);
    stage_unit(A, m0, 2 * i + 1, 1, lds[5], t, K);          // A1(T1)
    BAR(); mfma16(acc, 0, aF, bF0); BAR();
    lda4(aF, lds[1], arb, lr, lk);
    lda4(bF1, lds[3], brb, lr, lk);
    if (st) stage_unit(Bw, n0, 2 * i + 2, 0, lds[2], t, K); // B0(T2)
    BAR(); mfma16(acc, 0, aF, bF1); BAR();
    lda4(aF, lds[0], arb + 64, lr, lk);
    if (st) stage_unit(Bw, n0, 2 * i + 2, 1, lds[3], t, K); // B1(T2)
    BAR(); mfma16(acc, 1, aF, bF0); BAR();
    lda4(aF, lds[1], arb + 64, lr, lk);
    if (st) { stage_unit(A, m0, 2 * i + 2, 0, lds[0], t, K); VMCNT6(); }  // A0(T2)
    else    { VMCNT0(); }
    BAR(); mfma16(acc, 1, aF, bF1); BAR();
    // ---- tile 2i+1 from buf1 ----
    lda4(aF, lds[4], arb, lr, lk);
    lda4(bF0, lds[6], brb, lr, lk);
    if (st) stage_unit(A, m0, 2 * i + 2, 1, lds[1], t, K);  // A1(T2)
    BAR(); mfma16(acc, 0, aF, bF0); BAR();
    lda4(aF, lds[5], arb, lr, lk);
    lda4(bF1, lds[7], brb, lr, lk);
    if (st) stage_unit(Bw, n0, 2 * i + 3, 0, lds[6], t, K); // B0(T3)
    BAR(); mfma16(acc, 0, aF, bF1); BAR();
    lda4(aF, lds[4], arb + 64, lr, lk);
    if (st) stage_unit(Bw, n0, 2 * i + 3, 1, lds[7], t, K); // B1(T3)
    BAR(); mfma16(acc, 1, aF, bF0); BAR();
    lda4(aF, lds[5], arb + 64, lr, lk);
    if (st) { stage_unit(A, m0, 2 * i + 3, 0, lds[4], t, K); VMCNT6(); }  // A0(T3)
    BAR(); mfma16(acc, 1, aF, bF1); BAR();
  }

  // epilogue: C mapping col=lane&15, row=(lane>>4)*4+reg
#pragma unroll
  for (int mf = 0; mf < 8; ++mf) {
#pragma unroll
    for (int nf = 0; nf < 4; ++nf) {
      int n  = n0 + wn * 64 + nf * 16 + lr;
      int mb = m0 + wm * 128 + mf * 16 + lk * 4;
#pragma unroll
      for (int r = 0; r < 4; ++r) {
        if (MODE == 0) ((float*)Cout)[(size_t)(mb + r) * 1024 + n] = acc[mf][nf][r];
        else           ((u16*)Cout)[(size_t)(mb + r) * 1024 + n] = f2bf(acc[mf][nf][r]);
      }
    }
  }
}

// ===================== prep: weights->bf16 + w-row residuals, one kernel =====================
// blocks [0,520): in_proj bf16; [520,1032): out_proj bf16; [1032,1040): wlo residuals
__global__ __launch_bounds__(256) void prep_kernel(
    const float* __restrict__ ipw, const float* __restrict__ opw,
    u16* __restrict__ wbf_in, u16* __restrict__ wbf_out, u16* __restrict__ wlo)
{
  int b = blockIdx.x;
  if (b < 1032) {
    const float* src = (b < 520) ? ipw : opw;
    u16* dst = (b < 520) ? wbf_in : wbf_out;
    size_t i = ((size_t)(b < 520 ? b : b - 520) * 256 + threadIdx.x) * 8;
    f32x4 a = *reinterpret_cast<const f32x4*>(&src[i]);
    f32x4 c = *reinterpret_cast<const f32x4*>(&src[i + 4]);
    u16x8 o;
#pragma unroll
    for (int j = 0; j < 4; ++j) { o[j] = f2bf(a[j]); o[4 + j] = f2bf(c[j]); }
    *reinterpret_cast<u16x8*>(&dst[i]) = o;
  } else {
    size_t e = ((size_t)(b - 1032) * 256 + threadIdx.x) * 8;
    f32x4 a = *reinterpret_cast<const f32x4*>(&ipw[1048576 + e]);
    f32x4 c = *reinterpret_cast<const f32x4*>(&ipw[1048576 + e + 4]);
    u16x8 o;
#pragma unroll
    for (int j = 0; j < 4; ++j) {
      u16 h = f2bf(a[j]); o[j]     = f2bf(a[j] - bf2f(h));
      u16 g = f2bf(c[j]); o[4 + j] = f2bf(c[j] - bf2f(g));
    }
    *reinterpret_cast<u16x8*>(&wlo[e]) = o;
  }
}

// ===================== wsplit v4: K-split 4-wave x->bf16 + compensated w proj =====================
__global__ __launch_bounds__(256) void wsplit(
    const float* __restrict__ x, const u16* __restrict__ wbf, const u16* __restrict__ wlo,
    u16* __restrict__ xbf, float* __restrict__ wbufT)
{
  __shared__ u16 hi[4][16 * 5 * 8];   // 1.25 KB per wave
  __shared__ u16 lo[4][16 * 5 * 8];
  __shared__ float comb[3][64][4];
  const int t = threadIdx.x;
  const int w = t >> 6, l = t & 63;
  const int r0 = blockIdx.x * 16;
  const int k0 = w * 256;                   // this wave's k-quarter
  const int lr = l & 15, lk = l >> 4;
  const int srow = l >> 2, skc = l & 3;     // staging: lane -> row, k-chunk (8 floats)
  u16* HI = hi[w];
  u16* LO = lo[w];

  const float* gx  = &x[(size_t)(r0 + srow) * 1024 + k0 + skc * 8];
  const u16*   gbh = &wbf[(size_t)(1024 + lr) * 1024 + k0 + lk * 8];
  const u16*   gbl = &wlo[(size_t)lr * 1024 + k0 + lk * 8];

  f32x4 a0 = *reinterpret_cast<const f32x4*>(gx);
  f32x4 a1 = *reinterpret_cast<const f32x4*>(gx + 4);
  bf16x8 bh = *reinterpret_cast<const bf16x8*>(gbh);
  bf16x8 bl = *reinterpret_cast<const bf16x8*>(gbl);

  f32x4 acc = (f32x4){0.f, 0.f, 0.f, 0.f};
  const int wcell = srow * 5 + skc;
  const int rcell = lr * 5 + lk;

  for (int kt = 0; kt < 8; ++kt) {
    f32x4 n0, n1; bf16x8 nbh, nbl;
    if (kt < 7) {                  // prefetch next k-tile (x + w slices)
      n0  = *reinterpret_cast<const f32x4*>(gx + (kt + 1) * 32);
      n1  = *reinterpret_cast<const f32x4*>(gx + (kt + 1) * 32 + 4);
      nbh = *reinterpret_cast<const bf16x8*>(gbh + (kt + 1) * 32);
      nbl = *reinterpret_cast<const bf16x8*>(gbl + (kt + 1) * 32);
    }
    u16x8 h8, l8;
#pragma unroll
    for (int j = 0; j < 4; ++j) {
      u16 ha = f2bf(a0[j]); h8[j]     = ha; l8[j]     = f2bf(a0[j] - bf2f(ha));
      u16 hb = f2bf(a1[j]); h8[4 + j] = hb; l8[4 + j] = f2bf(a1[j] - bf2f(hb));
    }
    *reinterpret_cast<u16x8*>(&xbf[(size_t)(r0 + srow) * 1024 + k0 + kt * 32 + skc * 8]) = h8;
    *reinterpret_cast<u16x8*>(&HI[wcell * 8]) = h8;
    *reinterpret_cast<u16x8*>(&LO[wcell * 8]) = l8;
    asm volatile("s_waitcnt lgkmcnt(0)" ::: "memory");
    __builtin_amdgcn_sched_barrier(0);         // rule #18: pin MFMA below the wait
    bf16x8 ah = *reinterpret_cast<const bf16x8*>(&HI[rcell * 8]);
    bf16x8 al = *reinterpret_cast<const bf16x8*>(&LO[rcell * 8]);
    acc = __builtin_amdgcn_mfma_f32_16x16x32_bf16(ah, bh, acc, 0, 0, 0);
    acc = __builtin_amdgcn_mfma_f32_16x16x32_bf16(al, bh, acc, 0, 0, 0);
    acc = __builtin_amdgcn_mfma_f32_16x16x32_bf16(ah, bl, acc, 0, 0, 0);
    a0 = n0; a1 = n1; bh = nbh; bl = nbl;
  }
  // combine k-quarter partials, then store: h=lr, m = r0 + lk*4 + r
  if (w) {
#pragma unroll
    for (int r = 0; r < 4; ++r) comb[w - 1][l][r] = acc[r];
  }
  __syncthreads();
  if (!w) {
#pragma unroll
    for (int r = 0; r < 4; ++r) acc[r] += comb[0][l][r] + comb[1][l][r] + comb[2][l][r];
    *reinterpret_cast<f32x4*>(&wbufT[(size_t)lr * M_ + r0 + lk * 4]) = acc;
  }
}

// ===================== fused per-(b,h,c): conv + cumsum + L(MFMA) + Y_diag + norm + states =====================
__global__ __launch_bounds__(256) void chunk_kernel(
    const u16* __restrict__ xi,        // [M][1024] bf16 (in_proj out, pre-conv)
    const float* __restrict__ cw, const float* __restrict__ cb,
    const float* __restrict__ wbufT, const float* __restrict__ w_base,
    u16* __restrict__ ybuf, float* __restrict__ Acum, float* __restrict__ acbuf,
    float* __restrict__ normd, float* __restrict__ states, float* __restrict__ ndbuf)
{
  int bi = blockIdx.x;               // b*1024 + h*64 + c
  int c  = bi & 63;
  int h  = (bi >> 6) & 15;
  int b  = bi >> 10;
  int bh = b * 16 + h;
  int t  = threadIdx.x;
  __shared__ u16 xis[67][64];        // raw xi tile (halo 3), bf16
  __shared__ u16 xsT[64][66];        // conv output, transposed [n][s], bf16
  __shared__ float pc[CH], m1s[CH], dsv[CH];
  __shared__ float wls[4][64];       // conv weights transposed [tap][ch]
  __shared__ float cbs[64];
  size_t m0 = (size_t)b * S_ + (size_t)c * CH;
  size_t abase = ((size_t)bh * NC + c) * CH;

  wls[t & 3][t >> 2] = cw[(size_t)h * 256 + t];
  if (t < 64) cbs[t] = cb[h * 64 + t];

  {
    int g8  = t & 7;
    int hr0 = t >> 3;
    for (int hr = hr0; hr < 67; hr += 32) {
      u16x8 v = {0, 0, 0, 0, 0, 0, 0, 0};
      if (!(c == 0 && hr < 3))
        v = *reinterpret_cast<const u16x8*>(&xi[(m0 - 3 + hr) * DM + h * 64 + g8 * 8]);
      *reinterpret_cast<u16x8*>(&xis[hr][g8 * 8]) = v;
    }
  }

  if (t < 64) {
    float p = wbufT[(size_t)h * M_ + m0 + t] * w_base[h];
#pragma unroll
    for (int off = 1; off < 64; off <<= 1) {
      float v = __shfl_up(p, off);
      if (t >= off) p += v;
    }
    Acum[abase + t] = p;
    if (t == 63) acbuf[(size_t)bh * NC + c] = p;
    pc[t] = p;
    float rmin = p;
#pragma unroll
    for (int off = 1; off < 64; off <<= 1) {
      float v = __shfl_up(rmin, off);
      if (t >= off) rmin = fminf(rmin, v);
    }
    m1s[t] = p - rmin;
    float minall = __shfl(rmin, 63);
    dsv[t] = __expf(minall - p);
  }
  __syncthreads();

  // conv: thread owns channel n, 16 consecutive rows; sliding 4-tap window
  {
    int n  = t & 63;
    int lb = (t >> 6) * 16;
    float w0 = wls[0][n], w1 = wls[1][n], w2 = wls[2][n], w3 = wls[3][n];
    float bias = cbs[n];
    float a = bf2f(xis[lb + 0][n]);
    float bv = bf2f(xis[lb + 1][n]);
    float cv = bf2f(xis[lb + 2][n]);
    u16x8 o0, o1;
#pragma unroll
    for (int r = 0; r < 16; ++r) {
      float dv = bf2f(xis[lb + r + 3][n]);
      float s = fmaf(w3, dv, fmaf(w2, cv, fmaf(w1, bv, fmaf(w0, a, bias))));
      if (r < 8) o0[r] = f2bf(s); else o1[r - 8] = f2bf(s);
      a = bv; bv = cv; cv = dv;
    }
    *reinterpret_cast<u16x8*>(&xsT[n][lb]) = o0;
    *reinterpret_cast<u16x8*>(&xsT[n][lb + 8]) = o1;
  }
  __syncthreads();

  // MFMA phase: wave w owns output rows w*16..w*16+15.
  {
    int w = t >> 6, l = t & 63;
    int lr = l & 15, lk = l >> 4;
    int row = w * 16 + lr;
    float pr = pc[row], m1r = m1s[row];
    bf16x8 afr[2];
    float np = 0.f;
#pragma unroll
    for (int ks = 0; ks < 2; ++ks) {
      int sbase = ks * 32 + lk * 8;
      u16x8 av;
#pragma unroll
      for (int j = 0; j < 8; ++j) {
        int s = sbase + j;
        float L = (s <= row) ? __expf(pr - pc[s] - m1r) : 0.f;
        np += L;
        av[j] = f2bf(L);
      }
      afr[ks] = __builtin_bit_cast(bf16x8, av);
    }
    np += __shfl_xor(np, 16);
    np += __shfl_xor(np, 32);
    if (lk == 0) normd[abase + row] = np;

    f32x4 acc[4];
#pragma unroll
    for (int nf = 0; nf < 4; ++nf) acc[nf] = (f32x4){0.f, 0.f, 0.f, 0.f};
#pragma unroll
    for (int ks = 0; ks < 2; ++ks)
#pragma unroll
      for (int nf = 0; nf < 4; ++nf) {
        bf16x8 bfr = *reinterpret_cast<const bf16x8*>(&xsT[nf * 16 + lr][ks * 32 + lk * 8]);
        acc[nf] = __builtin_amdgcn_mfma_f32_16x16x32_bf16(afr[ks], bfr, acc[nf], 0, 0, 0);
      }
#pragma unroll
    for (int nf = 0; nf < 4; ++nf)
#pragma unroll
      for (int r = 0; r < 4; ++r)
        ybuf[(m0 + w * 16 + lk * 4 + r) * DM + h * 64 + nf * 16 + lr] = f2bf(acc[nf][r]);
  }

  if (t < 64) {
    float acc = 0.f;
#pragma unroll
    for (int l8 = 0; l8 < 64; l8 += 8) {
      u16x8 xv = *reinterpret_cast<const u16x8*>(&xsT[t][l8]);
#pragma unroll
      for (int j = 0; j < 8; ++j) acc = fmaf(dsv[l8 + j], bf2f(xv[j]), acc);
    }
    states[((size_t)bh * NC + c) * DN + t] = acc;
    float v = dsv[t];
#pragma unroll
    for (int off = 32; off >= 1; off >>= 1) v += __shfl_down(v, off);
    if (t == 0) ndbuf[(size_t)bh * NC + c] = v;
  }
}

// ===================== inter-chunk propagation =====================
__global__ __launch_bounds__(256) void interchunk_kernel(
    const float* __restrict__ acbuf, const float* __restrict__ states,
    const float* __restrict__ ndbuf, float* __restrict__ nstates, float* __restrict__ nndbuf)
{
  int bh = blockIdx.x;
  int t  = threadIdx.x;
  __shared__ float Ssum[NC], minP[NC], ndl[NC];
  if (t < 64) {
    float ac = acbuf[(size_t)bh * NC + t];
    float S = ac;
#pragma unroll
    for (int off = 1; off < 64; off <<= 1) {
      float v = __shfl_up(S, off);
      if (t >= off) S += v;
    }
    float Pc = S - ac;
    float mp = Pc;
#pragma unroll
    for (int off = 1; off < 64; off <<= 1) {
      float v = __shfl_up(mp, off);
      if (t >= off) mp = fminf(mp, v);
    }
    Ssum[t] = S;
    minP[t] = mp;
    ndl[t]  = ndbuf[(size_t)bh * NC + t];
  }
  __syncthreads();
  int n  = t & 63;
  int r0 = t >> 6;
  for (int r = 0; r < 16; ++r) {
    int z = r0 + r * 4;
    float mpz = minP[z];
    float acc = 0.f;
    for (int j = 0; j < z; ++j) {
      float e = __expf(mpz - Ssum[j]);
      acc = fmaf(e, states[((size_t)bh * NC + j) * DN + n], acc);
    }
    nstates[((size_t)bh * NC + z) * DN + n] = acc;
  }
  if (t < 64) {
    int z = t;
    float mpz = minP[z];
    float acc = 0.f;
    for (int j = 0; j < z; ++j) acc = fmaf(__expf(mpz - Ssum[j]), ndl[j], acc);
    nndbuf[(size_t)bh * NC + z] = acc;
  }
}

// ===================== final: y = (Y_diag + states_off*sdo) / (norm_diag + nd_off*sdo) =====================
__global__ __launch_bounds__(256) void final_kernel(
    const float* __restrict__ Acum, const float* __restrict__ normd,
    const float* __restrict__ nstates, const float* __restrict__ nndbuf,
    u16* __restrict__ ybuf)
{
  int bi = blockIdx.x;
  int c  = bi & 63;
  int h  = (bi >> 6) & 15;
  int b  = bi >> 10;
  int bh = b * 16 + h;
  int t  = threadIdx.x;
  __shared__ float sdo[CH], nrm[CH], sto[DN];
  __shared__ float ndo_s;
  size_t abase = ((size_t)bh * NC + c) * CH;
  if (t < 64) {
    float p = Acum[abase + t];
    float m3 = p;
#pragma unroll
    for (int off = 32; off >= 1; off >>= 1) m3 = fmaxf(m3, __shfl_down(m3, off));
    m3 = __shfl(m3, 0);
    sdo[t] = __expf(p - m3);
    nrm[t] = normd[abase + t];
    sto[t] = nstates[((size_t)bh * NC + c) * DN + t];
    if (t == 0) ndo_s = nndbuf[(size_t)bh * NC + c];
  }
  __syncthreads();
  size_t m0 = (size_t)b * S_ + (size_t)c * CH;
  int g  = t & 7;
  int l0 = t >> 3;
  float ndo = ndo_s;
  for (int li = l0; li < 64; li += 32) {
    size_t a = (m0 + li) * DM + h * DN + g * 8;
    u16x8 v = *reinterpret_cast<u16x8*>(&ybuf[a]);
    float sd = sdo[li];
    float rec = 1.f / (nrm[li] + ndo * sd);
    u16x8 o;
#pragma unroll
    for (int jj = 0; jj < 8; ++jj) {
      float yd = bf2f(v[jj]);
      o[jj] = f2bf((yd + sto[g * 8 + jj] * sd) * rec);
    }
    *reinterpret_cast<u16x8*>(&ybuf[a]) = o;
  }
}

// ===================== launch =====================
extern "C" void kernel_launch(void* const* d_in, const int* in_sizes, int n_in,
                              void* d_out, int out_size, void* d_ws, size_t ws_size,
                              hipStream_t stream) {
  const float* x          = (const float*)d_in[0];
  const float* in_proj_w  = (const float*)d_in[1];
  const float* conv_w     = (const float*)d_in[2];
  const float* conv_b     = (const float*)d_in[3];
  const float* w_base     = (const float*)d_in[4];
  const float* out_proj_w = (const float*)d_in[5];
  float* out = (float*)d_out;
  char* ws = (char*)d_ws;

  // workspace layout (~149 MB)
  u16*   wbf_in  = (u16*)  (ws + 0);          // [1040][1024] bf16 (all in_proj rows)
  u16*   wbf_out = (u16*)  (ws + 2129920);
  u16*   wlo16   = (u16*)  (ws + 4227072);    // [16][1024] bf16 residuals
  float* wbufT   = (float*)(ws + 4259840);
  float* Acum    = (float*)(ws + 6356992);
  float* acbuf   = (float*)(ws + 8454144);
  float* normd   = (float*)(ws + 8486912);
  float* states  = (float*)(ws + 10584064);
  float* ndbuf   = (float*)(ws + 12681216);
  float* nstates = (float*)(ws + 12713984);
  float* nndbuf  = (float*)(ws + 14811136);
  u16*   xbf     = (u16*)  (ws + 14843904);   // [M][1024] bf16 of x; reused as ybuf
  u16*   xibf    = (u16*)  (ws + 81952768);   // [M][1024] bf16 xi (in_proj out)
  u16*   ybuf    = xbf;

  prep_kernel<<<1040, 256, 0, stream>>>(in_proj_w, out_proj_w, wbf_in, wbf_out, wlo16);
  wsplit<<<2048, 256, 0, stream>>>(x, wbf_in, wlo16, xbf, wbufT);
  bgemm8<1><<<512, 512, 0, stream>>>(xbf, wbf_in, (void*)xibf, DM);
  chunk_kernel<<<8192, 256, 0, stream>>>(xibf, conv_w, conv_b, wbufT, w_base,
                                         ybuf, Acum, acbuf, normd, states, ndbuf);
  interchunk_kernel<<<128, 256, 0, stream>>>(acbuf, states, ndbuf, nstates, nndbuf);
  final_kernel<<<8192, 256, 0, stream>>>(Acum, normd, nstates, nndbuf, ybuf);
  bgemm8<0><<<512, 512, 0, stream>>>(ybuf, wbf_out, (void*)out, DM);
}

// Round 14
// 282.266 us; speedup vs baseline: 1.0489x; 1.0166x over previous
//
#include <hip/hip_runtime.h>
#include <hip/hip_bf16.h>
#include <cstdint>

#define B_ 8
#define S_ 4096
#define DM 1024
#define H_ 16
#define DN 64      // head dim
#define CH 64      // chunk length
#define NC 64      // chunks per sequence
#define M_ (B_ * S_)

typedef unsigned short u16;
typedef u16 u16x8 __attribute__((ext_vector_type(8)));
typedef u16 u16x4 __attribute__((ext_vector_type(4)));
typedef float f32x4 __attribute__((ext_vector_type(4)));
typedef __bf16 bf16x8 __attribute__((ext_vector_type(8)));

__device__ __forceinline__ float bf2f(u16 u) { return __uint_as_float(((unsigned)u) << 16); }
__device__ __forceinline__ u16 f2bf(float f) { __bf16 h = (__bf16)f; return __builtin_bit_cast(u16, h); }

#define GLOAD16(gp, lp) \
  __builtin_amdgcn_global_load_lds((__attribute__((address_space(1))) const void*)(gp), \
                                   (__attribute__((address_space(3))) void*)(lp), 16, 0, 0)
#define BAR()   asm volatile("s_barrier" ::: "memory")
#define VMCNT4() asm volatile("s_waitcnt vmcnt(4)" ::: "memory")
#define VMCNT0() asm volatile("s_waitcnt vmcnt(0)" ::: "memory")

// ===================== 256x256 single-barrier 8-phase bf16 MFMA GEMM =====================
// Round-14: rotation re-derived so EVERY restage is +2 phases after its slot's last
// read -> ONE barrier per phase is provably race-free (V's reads drain at its own
// lgkmcnt before MFMA(p), hence before V reaches BAR(p+1); restage at p+2 issues
// after passing BAR(p+1)). Read gating: vmcnt(4)+BAR at ph4/ph8 covers the next
// half-pair's reads (stage->read flight >= 4 phases). Barriers: 8 per 2 K-tiles
// (was 16). Stage map: ph1:A0b1 ph2:A1b1 ph3:B0b0' ph4:B1b0' ph5:A0b0' ph6:A1b0'
// ph7:B0b1' ph8:B1b1'.
__device__ __forceinline__ void stage_unit(const u16* __restrict__ src, int row0, int kt,
                                           int ks, u16* ldsu, int t, int K) {
#pragma unroll
  for (int i = 0; i < 2; ++i) {
    int f = i * 512 + t;
    int row = f >> 2, j = f & 3;
    int g = j ^ ((row >> 1) & 3);
    GLOAD16(src + (size_t)(row0 + row) * K + kt * 64 + ks * 32 + g * 8, ldsu + f * 8);
  }
}

__device__ __forceinline__ void lda4(bf16x8* fr, const u16* unit, int rbase, int lr, int lk) {
#pragma unroll
  for (int q = 0; q < 4; ++q) {
    int row = rbase + q * 16 + lr;
    int cell = row * 4 + (lk ^ ((row >> 1) & 3));
    fr[q] = *reinterpret_cast<const bf16x8*>(&unit[cell * 8]);
  }
}

__device__ __forceinline__ void mfma16(f32x4 (&acc)[8][4], int mh, const bf16x8* aF, const bf16x8* bF) {
  __builtin_amdgcn_s_setprio(1);
#pragma unroll
  for (int q = 0; q < 4; ++q)
#pragma unroll
    for (int nf = 0; nf < 4; ++nf)
      acc[mh * 4 + q][nf] = __builtin_amdgcn_mfma_f32_16x16x32_bf16(aF[q], bF[nf], acc[mh * 4 + q][nf], 0, 0, 0);
  __builtin_amdgcn_s_setprio(0);
}

template<int MODE>  // 0: fp32 out, 1: bf16 out
__global__ __launch_bounds__(512, 2) void bgemm8(
    const u16* __restrict__ A, const u16* __restrict__ Bw,
    void* __restrict__ Cout, int K)
{
  __shared__ u16 lds[8][8192];   // 0:A0b0 1:A1b0 2:B0b0 3:B1b0 4:A0b1 5:A1b1 6:B0b1 7:B1b1
  const int orig = blockIdx.x;                        // 512 blocks, 512 % 8 == 0
  const int swz  = (orig & 7) * 64 + (orig >> 3);     // XCD-bijective
  const int m0 = (swz >> 2) * 256;
  const int n0 = (swz & 3) * 256;
  const int t  = threadIdx.x;
  const int wid = t >> 6, l = t & 63;
  const int wm = wid >> 2, wn = wid & 3;
  const int lr = l & 15, lk = l >> 4;
  const int arb = wm * 128;     // A row base for this wave
  const int brb = wn * 64;      // B row base

  f32x4 acc[8][4];
#pragma unroll
  for (int i = 0; i < 8; ++i)
#pragma unroll
    for (int j = 0; j < 4; ++j) acc[i][j] = (f32x4){0.f, 0.f, 0.f, 0.f};

  // prologue: b0 units for tile 0, B of b1 for tile 1 (A of b1 staged at ph1/ph2).
  // Order matters for vmcnt(4): oldest 4 stages = the 4 units ph1/ph2 read.
  stage_unit(A,  m0, 0, 0, lds[0], t, K);
  stage_unit(Bw, n0, 0, 0, lds[2], t, K);
  stage_unit(A,  m0, 0, 1, lds[1], t, K);
  stage_unit(Bw, n0, 0, 1, lds[3], t, K);
  stage_unit(Bw, n0, 1, 0, lds[6], t, K);
  stage_unit(Bw, n0, 1, 1, lds[7], t, K);
  VMCNT4();   // drain lds[0],[2],[1],[3]
  BAR();

  bf16x8 aF[4], bF0[4], bF1[4];
  for (int i = 0; i < 8; ++i) {
    const bool st = (i < 7);
    // ph1 (tile 2i, mh0, ks0)
    lda4(aF, lds[0], arb, lr, lk);
    lda4(bF0, lds[2], brb, lr, lk);
    stage_unit(A, m0, 2 * i + 1, 0, lds[4], t, K);          // A0b1 <- A_ks0(2i+1)
    BAR(); mfma16(acc, 0, aF, bF0);
    // ph2 (tile 2i, mh0, ks1)
    lda4(aF, lds[1], arb, lr, lk);
    lda4(bF1, lds[3], brb, lr, lk);
    stage_unit(A, m0, 2 * i + 1, 1, lds[5], t, K);          // A1b1 <- A_ks1(2i+1)
    BAR(); mfma16(acc, 0, aF, bF1);
    // ph3 (tile 2i, mh1, ks0)  [bF0 register-held]
    lda4(aF, lds[0], arb + 64, lr, lk);
    if (st) stage_unit(Bw, n0, 2 * i + 2, 0, lds[2], t, K); // B0b0 <- B_ks0(2i+2)
    BAR(); mfma16(acc, 1, aF, bF0);
    // ph4 (tile 2i, mh1, ks1) + wait gating ph5/ph6 reads
    lda4(aF, lds[1], arb + 64, lr, lk);
    if (st) stage_unit(Bw, n0, 2 * i + 2, 1, lds[3], t, K); // B1b0 <- B_ks1(2i+2)
    if (st) VMCNT4(); else VMCNT0();
    BAR(); mfma16(acc, 1, aF, bF1);
    // ph5 (tile 2i+1, mh0, ks0)
    lda4(aF, lds[4], arb, lr, lk);
    lda4(bF0, lds[6], brb, lr, lk);
    if (st) stage_unit(A, m0, 2 * i + 2, 0, lds[0], t, K);  // A0b0 <- A_ks0(2i+2)
    BAR(); mfma16(acc, 0, aF, bF0);
    // ph6 (tile 2i+1, mh0, ks1)
    lda4(aF, lds[5], arb, lr, lk);
    lda4(bF1, lds[7], brb, lr, lk);
    if (st) stage_unit(A, m0, 2 * i + 2, 1, lds[1], t, K);  // A1b0 <- A_ks1(2i+2)
    BAR(); mfma16(acc, 0, aF, bF1);
    // ph7 (tile 2i+1, mh1, ks0)
    lda4(aF, lds[4], arb + 64, lr, lk);
    if (st) stage_unit(Bw, n0, 2 * i + 3, 0, lds[6], t, K); // B0b1 <- B_ks0(2i+3)
    BAR(); mfma16(acc, 1, aF, bF0);
    // ph8 (tile 2i+1, mh1, ks1) + wait gating next pair's ph1/ph2 reads
    lda4(aF, lds[5], arb + 64, lr, lk);
    if (st) stage_unit(Bw, n0, 2 * i + 3, 1, lds[7], t, K); // B1b1 <- B_ks1(2i+3)
    if (st) VMCNT4();
    BAR(); mfma16(acc, 1, aF, bF1);
  }

  // epilogue: C mapping col=lane&15, row=(lane>>4)*4+reg
#pragma unroll
  for (int mf = 0; mf < 8; ++mf) {
#pragma unroll
    for (int nf = 0; nf < 4; ++nf) {
      int n  = n0 + wn * 64 + nf * 16 + lr;
      int mb = m0 + wm * 128 + mf * 16 + lk * 4;
#pragma unroll
      for (int r = 0; r < 4; ++r) {
        if (MODE == 0) ((float*)Cout)[(size_t)(mb + r) * 1024 + n] = acc[mf][nf][r];
        else           ((u16*)Cout)[(size_t)(mb + r) * 1024 + n] = f2bf(acc[mf][nf][r]);
      }
    }
  }
}

// ===================== prep: weights->bf16 + w-row residuals, one kernel =====================
__global__ __launch_bounds__(256) void prep_kernel(
    const float* __restrict__ ipw, const float* __restrict__ opw,
    u16* __restrict__ wbf_in, u16* __restrict__ wbf_out, u16* __restrict__ wlo)
{
  int b = blockIdx.x;
  if (b < 1032) {
    const float* src = (b < 520) ? ipw : opw;
    u16* dst = (b < 520) ? wbf_in : wbf_out;
    size_t i = ((size_t)(b < 520 ? b : b - 520) * 256 + threadIdx.x) * 8;
    f32x4 a = *reinterpret_cast<const f32x4*>(&src[i]);
    f32x4 c = *reinterpret_cast<const f32x4*>(&src[i + 4]);
    u16x8 o;
#pragma unroll
    for (int j = 0; j < 4; ++j) { o[j] = f2bf(a[j]); o[4 + j] = f2bf(c[j]); }
    *reinterpret_cast<u16x8*>(&dst[i]) = o;
  } else {
    size_t e = ((size_t)(b - 1032) * 256 + threadIdx.x) * 8;
    f32x4 a = *reinterpret_cast<const f32x4*>(&ipw[1048576 + e]);
    f32x4 c = *reinterpret_cast<const f32x4*>(&ipw[1048576 + e + 4]);
    u16x8 o;
#pragma unroll
    for (int j = 0; j < 4; ++j) {
      u16 h = f2bf(a[j]); o[j]     = f2bf(a[j] - bf2f(h));
      u16 g = f2bf(c[j]); o[4 + j] = f2bf(c[j] - bf2f(g));
    }
    *reinterpret_cast<u16x8*>(&wlo[e]) = o;
  }
}

// ===================== wsplit v4: K-split 4-wave x->bf16 + compensated w proj =====================
__global__ __launch_bounds__(256) void wsplit(
    const float* __restrict__ x, const u16* __restrict__ wbf, const u16* __restrict__ wlo,
    u16* __restrict__ xbf, float* __restrict__ wbufT)
{
  __shared__ u16 hi[4][16 * 5 * 8];   // 1.25 KB per wave
  __shared__ u16 lo[4][16 * 5 * 8];
  __shared__ float comb[3][64][4];
  const int t = threadIdx.x;
  const int w = t >> 6, l = t & 63;
  const int r0 = blockIdx.x * 16;
  const int k0 = w * 256;                   // this wave's k-quarter
  const int lr = l & 15, lk = l >> 4;
  const int srow = l >> 2, skc = l & 3;     // staging: lane -> row, k-chunk (8 floats)
  u16* HI = hi[w];
  u16* LO = lo[w];

  const float* gx  = &x[(size_t)(r0 + srow) * 1024 + k0 + skc * 8];
  const u16*   gbh = &wbf[(size_t)(1024 + lr) * 1024 + k0 + lk * 8];
  const u16*   gbl = &wlo[(size_t)lr * 1024 + k0 + lk * 8];

  f32x4 a0 = *reinterpret_cast<const f32x4*>(gx);
  f32x4 a1 = *reinterpret_cast<const f32x4*>(gx + 4);
  bf16x8 bh = *reinterpret_cast<const bf16x8*>(gbh);
  bf16x8 bl = *reinterpret_cast<const bf16x8*>(gbl);

  f32x4 acc = (f32x4){0.f, 0.f, 0.f, 0.f};
  const int wcell = srow * 5 + skc;
  const int rcell = lr * 5 + lk;

  for (int kt = 0; kt < 8; ++kt) {
    f32x4 n0, n1; bf16x8 nbh, nbl;
    if (kt < 7) {                  // prefetch next k-tile (x + w slices)
      n0  = *reinterpret_cast<const f32x4*>(gx + (kt + 1) * 32);
      n1  = *reinterpret_cast<const f32x4*>(gx + (kt + 1) * 32 + 4);
      nbh = *reinterpret_cast<const bf16x8*>(gbh + (kt + 1) * 32);
      nbl = *reinterpret_cast<const bf16x8*>(gbl + (kt + 1) * 32);
    }
    u16x8 h8, l8;
#pragma unroll
    for (int j = 0; j < 4; ++j) {
      u16 ha = f2bf(a0[j]); h8[j]     = ha; l8[j]     = f2bf(a0[j] - bf2f(ha));
      u16 hb = f2bf(a1[j]); h8[4 + j] = hb; l8[4 + j] = f2bf(a1[j] - bf2f(hb));
    }
    *reinterpret_cast<u16x8*>(&xbf[(size_t)(r0 + srow) * 1024 + k0 + kt * 32 + skc * 8]) = h8;
    *reinterpret_cast<u16x8*>(&HI[wcell * 8]) = h8;
    *reinterpret_cast<u16x8*>(&LO[wcell * 8]) = l8;
    asm volatile("s_waitcnt lgkmcnt(0)" ::: "memory");
    __builtin_amdgcn_sched_barrier(0);         // rule #18: pin MFMA below the wait
    bf16x8 ah = *reinterpret_cast<const bf16x8*>(&HI[rcell * 8]);
    bf16x8 al = *reinterpret_cast<const bf16x8*>(&LO[rcell * 8]);
    acc = __builtin_amdgcn_mfma_f32_16x16x32_bf16(ah, bh, acc, 0, 0, 0);
    acc = __builtin_amdgcn_mfma_f32_16x16x32_bf16(al, bh, acc, 0, 0, 0);
    acc = __builtin_amdgcn_mfma_f32_16x16x32_bf16(ah, bl, acc, 0, 0, 0);
    a0 = n0; a1 = n1; bh = nbh; bl = nbl;
  }
  // combine k-quarter partials, then store: h=lr, m = r0 + lk*4 + r
  if (w) {
#pragma unroll
    for (int r = 0; r < 4; ++r) comb[w - 1][l][r] = acc[r];
  }
  __syncthreads();
  if (!w) {
#pragma unroll
    for (int r = 0; r < 4; ++r) acc[r] += comb[0][l][r] + comb[1][l][r] + comb[2][l][r];
    *reinterpret_cast<f32x4*>(&wbufT[(size_t)lr * M_ + r0 + lk * 4]) = acc;
  }
}

// ===================== fused per-(b,h,c): conv + cumsum + L(MFMA) + Y_diag + norm + states =====================
__global__ __launch_bounds__(256) void chunk_kernel(
    const u16* __restrict__ xi,        // [M][1024] bf16 (in_proj out, pre-conv)
    const float* __restrict__ cw, const float* __restrict__ cb,
    const float* __restrict__ wbufT, const float* __restrict__ w_base,
    u16* __restrict__ ybuf, float* __restrict__ Acum, float* __restrict__ acbuf,
    float* __restrict__ normd, float* __restrict__ states, float* __restrict__ ndbuf)
{
  int bi = blockIdx.x;               // b*1024 + h*64 + c
  int c  = bi & 63;
  int h  = (bi >> 6) & 15;
  int b  = bi >> 10;
  int bh = b * 16 + h;
  int t  = threadIdx.x;
  __shared__ u16 xis[67][64];        // raw xi tile (halo 3), bf16
  __shared__ u16 xsT[64][66];        // conv output, transposed [n][s], bf16
  __shared__ float pc[CH], m1s[CH], dsv[CH];
  __shared__ float wls[4][64];       // conv weights transposed [tap][ch]
  __shared__ float cbs[64];
  size_t m0 = (size_t)b * S_ + (size_t)c * CH;
  size_t abase = ((size_t)bh * NC + c) * CH;

  wls[t & 3][t >> 2] = cw[(size_t)h * 256 + t];
  if (t < 64) cbs[t] = cb[h * 64 + t];

  {
    int g8  = t & 7;
    int hr0 = t >> 3;
    for (int hr = hr0; hr < 67; hr += 32) {
      u16x8 v = {0, 0, 0, 0, 0, 0, 0, 0};
      if (!(c == 0 && hr < 3))
        v = *reinterpret_cast<const u16x8*>(&xi[(m0 - 3 + hr) * DM + h * 64 + g8 * 8]);
      *reinterpret_cast<u16x8*>(&xis[hr][g8 * 8]) = v;
    }
  }

  if (t < 64) {
    float p = wbufT[(size_t)h * M_ + m0 + t] * w_base[h];
#pragma unroll
    for (int off = 1; off < 64; off <<= 1) {
      float v = __shfl_up(p, off);
      if (t >= off) p += v;
    }
    Acum[abase + t] = p;
    if (t == 63) acbuf[(size_t)bh * NC + c] = p;
    pc[t] = p;
    float rmin = p;
#pragma unroll
    for (int off = 1; off < 64; off <<= 1) {
      float v = __shfl_up(rmin, off);
      if (t >= off) rmin = fminf(rmin, v);
    }
    m1s[t] = p - rmin;
    float minall = __shfl(rmin, 63);
    dsv[t] = __expf(minall - p);
  }
  __syncthreads();

  // conv: thread owns channel n, 16 consecutive rows; sliding 4-tap window
  {
    int n  = t & 63;
    int lb = (t >> 6) * 16;
    float w0 = wls[0][n], w1 = wls[1][n], w2 = wls[2][n], w3 = wls[3][n];
    float bias = cbs[n];
    float a = bf2f(xis[lb + 0][n]);
    float bv = bf2f(xis[lb + 1][n]);
    float cv = bf2f(xis[lb + 2][n]);
    u16x8 o0, o1;
#pragma unroll
    for (int r = 0; r < 16; ++r) {
      float dv = bf2f(xis[lb + r + 3][n]);
      float s = fmaf(w3, dv, fmaf(w2, cv, fmaf(w1, bv, fmaf(w0, a, bias))));
      if (r < 8) o0[r] = f2bf(s); else o1[r - 8] = f2bf(s);
      a = bv; bv = cv; cv = dv;
    }
    *reinterpret_cast<u16x8*>(&xsT[n][lb]) = o0;
    *reinterpret_cast<u16x8*>(&xsT[n][lb + 8]) = o1;
  }
  __syncthreads();

  // MFMA phase: wave w owns output rows w*16..w*16+15.
  {
    int w = t >> 6, l = t & 63;
    int lr = l & 15, lk = l >> 4;
    int row = w * 16 + lr;
    float pr = pc[row], m1r = m1s[row];
    bf16x8 afr[2];
    float np = 0.f;
#pragma unroll
    for (int ks = 0; ks < 2; ++ks) {
      int sbase = ks * 32 + lk * 8;
      u16x8 av;
#pragma unroll
      for (int j = 0; j < 8; ++j) {
        int s = sbase + j;
        float L = (s <= row) ? __expf(pr - pc[s] - m1r) : 0.f;
        np += L;
        av[j] = f2bf(L);
      }
      afr[ks] = __builtin_bit_cast(bf16x8, av);
    }
    np += __shfl_xor(np, 16);
    np += __shfl_xor(np, 32);
    if (lk == 0) normd[abase + row] = np;

    f32x4 acc[4];
#pragma unroll
    for (int nf = 0; nf < 4; ++nf) acc[nf] = (f32x4){0.f, 0.f, 0.f, 0.f};
#pragma unroll
    for (int ks = 0; ks < 2; ++ks)
#pragma unroll
      for (int nf = 0; nf < 4; ++nf) {
        bf16x8 bfr = *reinterpret_cast<const bf16x8*>(&xsT[nf * 16 + lr][ks * 32 + lk * 8]);
        acc[nf] = __builtin_amdgcn_mfma_f32_16x16x32_bf16(afr[ks], bfr, acc[nf], 0, 0, 0);
      }
#pragma unroll
    for (int nf = 0; nf < 4; ++nf)
#pragma unroll
      for (int r = 0; r < 4; ++r)
        ybuf[(m0 + w * 16 + lk * 4 + r) * DM + h * 64 + nf * 16 + lr] = f2bf(acc[nf][r]);
  }

  if (t < 64) {
    float acc = 0.f;
#pragma unroll
    for (int l8 = 0; l8 < 64; l8 += 8) {
      u16x8 xv = *reinterpret_cast<const u16x8*>(&xsT[t][l8]);
#pragma unroll
      for (int j = 0; j < 8; ++j) acc = fmaf(dsv[l8 + j], bf2f(xv[j]), acc);
    }
    states[((size_t)bh * NC + c) * DN + t] = acc;
    float v = dsv[t];
#pragma unroll
    for (int off = 32; off >= 1; off >>= 1) v += __shfl_down(v, off);
    if (t == 0) ndbuf[(size_t)bh * NC + c] = v;
  }
}

// ===================== inter-chunk propagation =====================
__global__ __launch_bounds__(256) void interchunk_kernel(
    const float* __restrict__ acbuf, const float* __restrict__ states,
    const float* __restrict__ ndbuf, float* __restrict__ nstates, float* __restrict__ nndbuf)
{
  int bh = blockIdx.x;
  int t  = threadIdx.x;
  __shared__ float Ssum[NC], minP[NC], ndl[NC];
  if (t < 64) {
    float ac = acbuf[(size_t)bh * NC + t];
    float S = ac;
#pragma unroll
    for (int off = 1; off < 64; off <<= 1) {
      float v = __shfl_up(S, off);
      if (t >= off) S += v;
    }
    float Pc = S - ac;
    float mp = Pc;
#pragma unroll
    for (int off = 1; off < 64; off <<= 1) {
      float v = __shfl_up(mp, off);
      if (t >= off) mp = fminf(mp, v);
    }
    Ssum[t] = S;
    minP[t] = mp;
    ndl[t]  = ndbuf[(size_t)bh * NC + t];
  }
  __syncthreads();
  int n  = t & 63;
  int r0 = t >> 6;
  for (int r = 0; r < 16; ++r) {
    int z = r0 + r * 4;
    float mpz = minP[z];
    float acc = 0.f;
    for (int j = 0; j < z; ++j) {
      float e = __expf(mpz - Ssum[j]);
      acc = fmaf(e, states[((size_t)bh * NC + j) * DN + n], acc);
    }
    nstates[((size_t)bh * NC + z) * DN + n] = acc;
  }
  if (t < 64) {
    int z = t;
    float mpz = minP[z];
    float acc = 0.f;
    for (int j = 0; j < z; ++j) acc = fmaf(__expf(mpz - Ssum[j]), ndl[j], acc);
    nndbuf[(size_t)bh * NC + z] = acc;
  }
}

// ===================== final: y = (Y_diag + states_off*sdo) / (norm_diag + nd_off*sdo) =====================
__global__ __launch_bounds__(256) void final_kernel(
    const float* __restrict__ Acum, const float* __restrict__ normd,
    const float* __restrict__ nstates, const float* __restrict__ nndbuf,
    u16* __restrict__ ybuf)
{
  int bi = blockIdx.x;
  int c  = bi & 63;
  int h  = (bi >> 6) & 15;
  int b  = bi >> 10;
  int bh = b * 16 + h;
  int t  = threadIdx.x;
  __shared__ float sdo[CH], nrm[CH], sto[DN];
  __shared__ float ndo_s;
  size_t abase = ((size_t)bh * NC + c) * CH;
  if (t < 64) {
    float p = Acum[abase + t];
    float m3 = p;
#pragma unroll
    for (int off = 32; off >= 1; off >>= 1) m3 = fmaxf(m3, __shfl_down(m3, off));
    m3 = __shfl(m3, 0);
    sdo[t] = __expf(p - m3);
    nrm[t] = normd[abase + t];
    sto[t] = nstates[((size_t)bh * NC + c) * DN + t];
    if (t == 0) ndo_s = nndbuf[(size_t)bh * NC + c];
  }
  __syncthreads();
  size_t m0 = (size_t)b * S_ + (size_t)c * CH;
  int g  = t & 7;
  int l0 = t >> 3;
  float ndo = ndo_s;
  for (int li = l0; li < 64; li += 32) {
    size_t a = (m0 + li) * DM + h * DN + g * 8;
    u16x8 v = *reinterpret_cast<u16x8*>(&ybuf[a]);
    float sd = sdo[li];
    float rec = 1.f / (nrm[li] + ndo * sd);
    u16x8 o;
#pragma unroll
    for (int jj = 0; jj < 8; ++jj) {
      float yd = bf2f(v[jj]);
      o[jj] = f2bf((yd + sto[g * 8 + jj] * sd) * rec);
    }
    *reinterpret_cast<u16x8*>(&ybuf[a]) = o;
  }
}

// ===================== launch =====================
extern "C" void kernel_launch(void* const* d_in, const int* in_sizes, int n_in,
                              void* d_out, int out_size, void* d_ws, size_t ws_size,
                              hipStream_t stream) {
  const float* x          = (const float*)d_in[0];
  const float* in_proj_w  = (const float*)d_in[1];
  const float* conv_w     = (const float*)d_in[2];
  const float* conv_b     = (const float*)d_in[3];
  const float* w_base     = (const float*)d_in[4];
  const float* out_proj_w = (const float*)d_in[5];
  float* out = (float*)d_out;
  char* ws = (char*)d_ws;

  // workspace layout (~149 MB)
  u16*   wbf_in  = (u16*)  (ws + 0);          // [1040][1024] bf16 (all in_proj rows)
  u16*   wbf_out = (u16*)  (ws + 2129920);
  u16*   wlo16   = (u16*)  (ws + 4227072);    // [16][1024] bf16 residuals
  float* wbufT   = (float*)(ws + 4259840);
  float* Acum    = (float*)(ws + 6356992);
  float* acbuf   = (float*)(ws + 8454144);
  float* normd   = (float*)(ws + 8486912);
  float* states  = (float*)(ws + 10584064);
  float* ndbuf   = (float*)(ws + 12681216);
  float* nstates = (float*)(ws + 12713984);
  float* nndbuf  = (float*)(ws + 14811136);
  u16*   xbf     = (u16*)  (ws + 14843904);   // [M][1024] bf16 of x; reused as ybuf
  u16*   xibf    = (u16*)  (ws + 81952768);   // [M][1024] bf16 xi (in_proj out)
  u16*   ybuf    = xbf;

  prep_kernel<<<1040, 256, 0, stream>>>(in_proj_w, out_proj_w, wbf_in, wbf_out, wlo16);
  wsplit<<<2048, 256, 0, stream>>>(x, wbf_in, wlo16, xbf, wbufT);
  bgemm8<1><<<512, 512, 0, stream>>>(xbf, wbf_in, (void*)xibf, DM);
  chunk_kernel<<<8192, 256, 0, stream>>>(xibf, conv_w, conv_b, wbufT, w_base,
                                         ybuf, Acum, acbuf, normd, states, ndbuf);
  interchunk_kernel<<<128, 256, 0, stream>>>(acbuf, states, ndbuf, nstates, nndbuf);
  final_kernel<<<8192, 256, 0, stream>>>(Acum, normd, nstates, nndbuf, ybuf);
  bgemm8<0><<<512, 512, 0, stream>>>(ybuf, wbf_out, (void*)out, DM);
}